// Round 1
// baseline (811.616 us; speedup 1.0000x reference)
//
#include <hip/hip_runtime.h>

// Problem dims (fixed by reference):
//   x:      [M=16384, K=8192] fp32
//   weight: [N=8192,  K=8192] fp32
//   out:    [M, 1] fp32 = 0.75 * x @ colsum(weight)
#define M_DIM 16384
#define N_DIM 8192
#define K_DIM 8192

// ---------------- Kernel 1: column sum of weight ----------------
// weight is [N, K] row-major. colsum[k] = sum_n weight[n*K + k].
// Each thread owns 4 consecutive columns (float4). Grid:
//   grid.x = K/4/256 = 8 column-blocks
//   grid.y = 128 row-splits, each covering N/128 = 64 rows
// Per-thread register accumulation over 64 rows, then 4 atomicAdds.
#define ROW_SPLITS 128
#define ROWS_PER_SPLIT (N_DIM / ROW_SPLITS)   // 64

__global__ __launch_bounds__(256) void colsum_kernel(const float* __restrict__ W,
                                                     float* __restrict__ colsum) {
    const int col4 = blockIdx.x * 256 + threadIdx.x;      // float4 index in [0, K/4)
    const int row0 = blockIdx.y * ROWS_PER_SPLIT;
    const float4* __restrict__ Wv = reinterpret_cast<const float4*>(W);
    const int k4 = K_DIM / 4;

    float ax = 0.f, ay = 0.f, az = 0.f, aw = 0.f;
    size_t base = (size_t)row0 * k4 + col4;
#pragma unroll 8
    for (int r = 0; r < ROWS_PER_SPLIT; ++r) {
        float4 v = Wv[base + (size_t)r * k4];
        ax += v.x; ay += v.y; az += v.z; aw += v.w;
    }
    float* dst = colsum + (size_t)col4 * 4;
    atomicAdd(dst + 0, ax);
    atomicAdd(dst + 1, ay);
    atomicAdd(dst + 2, az);
    atomicAdd(dst + 3, aw);
}

// ---------------- Kernel 2: out[m] = 0.75 * dot(x[m,:], colsum) ----------------
// One 256-thread block per row. Each thread: 8 float4 chunks. colsum (32 KB)
// is L2-resident across all 16384 blocks.
__global__ __launch_bounds__(256) void matvec_kernel(const float* __restrict__ x,
                                                     const float* __restrict__ colsum,
                                                     float* __restrict__ out) {
    const int m = blockIdx.x;
    const float4* __restrict__ xv =
        reinterpret_cast<const float4*>(x + (size_t)m * K_DIM);
    const float4* __restrict__ cv = reinterpret_cast<const float4*>(colsum);

    float acc = 0.f;
#pragma unroll
    for (int i = 0; i < (K_DIM / 4) / 256; ++i) {   // 8 iters
        const int idx = threadIdx.x + i * 256;
        float4 a = xv[idx];
        float4 c = cv[idx];
        acc += a.x * c.x + a.y * c.y + a.z * c.z + a.w * c.w;
    }

    // wave (64-lane) shuffle reduction
#pragma unroll
    for (int off = 32; off > 0; off >>= 1)
        acc += __shfl_down(acc, off, 64);

    __shared__ float s[4];
    const int lane = threadIdx.x & 63;
    const int wave = threadIdx.x >> 6;
    if (lane == 0) s[wave] = acc;
    __syncthreads();
    if (threadIdx.x == 0)
        out[m] = 0.75f * (s[0] + s[1] + s[2] + s[3]);
}

extern "C" void kernel_launch(void* const* d_in, const int* in_sizes, int n_in,
                              void* d_out, int out_size, void* d_ws, size_t ws_size,
                              hipStream_t stream) {
    const float* x = (const float*)d_in[0];       // [M, K]
    const float* w = (const float*)d_in[1];       // [N, K]
    float* out = (float*)d_out;                   // [M]
    float* colsum = (float*)d_ws;                 // K floats = 32 KB scratch

    // d_ws is poisoned (0xAA) before every timed call — zero the colsum buffer.
    hipMemsetAsync(colsum, 0, K_DIM * sizeof(float), stream);

    dim3 g1(K_DIM / 4 / 256, ROW_SPLITS);         // (8, 128) = 1024 blocks
    colsum_kernel<<<g1, 256, 0, stream>>>(w, colsum);

    matvec_kernel<<<M_DIM, 256, 0, stream>>>(x, colsum, out);
}